// Round 7
// baseline (279.369 us; speedup 1.0000x reference)
//
#include <hip/hip_runtime.h>

namespace {

constexpr int B = 64, N = 64, D = 64, E = 2 * D + 1;  // E = 129
constexpr int NBLK = 256;
constexpr size_t MAXSLOT = 1024;
constexpr int LMAX = 8;

__device__ __forceinline__ float4 f4ld(const float* p) { return *(const float4*)p; }
__device__ __forceinline__ void f4acc(float4& a, const float4 b) {
  a.x += b.x; a.y += b.y; a.z += b.z; a.w += b.w;
}

// Device-scope grid barrier: release fence -> arrive -> RMW-poll -> acquire fence.
// Counters are zeroed by a memset node before the kernel each call.
__device__ __forceinline__ void gridbar(unsigned* cnt) {
  __syncthreads();
  if (threadIdx.x == 0) {
    __threadfence();                       // release: flush L2 (cross-XCD)
    atomicAdd(cnt, 1u);
    while (atomicAdd(cnt, 0u) < (unsigned)NBLK) __builtin_amdgcn_s_sleep(8);
    __threadfence();                       // acquire: invalidate stale L1/L2
  }
  __syncthreads();
}

__global__ __launch_bounds__(256) void k_fused(
    const float* __restrict__ x,   // [B][N][D]
    const float* __restrict__ ew,  // [N][N]
    const float* __restrict__ Wm,  // [L][N][N][E][D]
    const float* __restrict__ bm,  // [L][N][N][D]
    const float* __restrict__ Wu,  // [L][2D][D]
    const float* __restrict__ bu,  // [L][D]
    const float* __restrict__ Wo,  // [D][D]
    const float* __restrict__ bo,  // [D]
    float* __restrict__ out,       // [B][D]
    char* __restrict__ ws, int L)
{
  // ---- workspace carve (bar at offset 0; memset-zeroed each launch) ----
  unsigned* bar = (unsigned*)ws;
  char* p = ws + 256;
  float* s       = (float*)p; p += (size_t)B * N * D * 4;
  float* selfmsg = (float*)p; p += (size_t)N * B * D * 4;
  float* msg     = (float*)p; p += MAXSLOT * B * D * 4;
  float* sw1     = (float*)p; p += (size_t)LMAX * N * D * D * 4;
  float* baseB   = (float*)p; p += (size_t)LMAX * N * D * 4;
  uint4* nbr4    = (uint4*)p; p += N * 16;
  float* degf    = (float*)p; p += N * 4;
  float* cwg     = (float*)p; p += N * 4;
  int* cntg      = (int*)p;   p += N * 4;
  int* rowbase   = (int*)p;   p += N * 4;
  int* edgeIJ    = (int*)p;   p += MAXSLOT * 4;
  int* nedg      = (int*)p;   p += 16;
  unsigned char* nfull = (unsigned char*)p;  // [N][N]

  __shared__ __align__(16) char pool[51200];

  const int g = blockIdx.x;
  const int t = threadIdx.x;

  // ================= P0: prep (block 0) + W1-sum/base (blocks 1..L*N) ======
  if (g == 0) {
    if (t < N) {
      int rc = 0;
      for (int j = 0; j < N; ++j) rc += (ew[t * N + j] > 0.f) ? 1 : 0;
      int pre = rc;
#pragma unroll
      for (int off = 1; off < 64; off <<= 1) {
        int v = __shfl_up(pre, off, 64);
        if (t >= off) pre += v;
      }
      const int base = pre - rc;  // exclusive prefix
      rowbase[t] = base;
      unsigned long long lo = 0ull, hi = 0ull;
      int c = 0;
      float rowsum = 0.f;
      for (int j = 0; j < N; ++j) {
        const float v = ew[t * N + j];
        rowsum += v;
        if (v > 0.f) {
          edgeIJ[base + c] = t * N + j;
          if (c < 8)       lo |= (unsigned long long)j << (c * 8);
          else if (c < 16) hi |= (unsigned long long)j << ((c - 8) * 8);
          nfull[t * N + c] = (unsigned char)j;
          ++c;
        }
      }
      uint4 w4;
      w4.x = (unsigned)lo; w4.y = (unsigned)(lo >> 32);
      w4.z = (unsigned)hi; w4.w = (unsigned)(hi >> 32);
      nbr4[t] = w4; cntg[t] = c; degf[t] = (float)c;
      float tot = rowsum;
#pragma unroll
      for (int off = 32; off >= 1; off >>= 1) tot += __shfl_xor(tot, off, 64);
      cwg[t] = rowsum / (tot + 1e-8f);
      if (t == 63) *nedg = pre;  // total edge count
    }
  } else if (g <= L * N) {
    // SW1[l][i] = sum_{j in N(i)} W1_{l,i,j};  base[l][i] = sum_j (w*W3 + b)
    const int unit = g - 1, l = unit >> 6, i = unit & 63;
    const float* Wl = Wm + (size_t)l * N * N * E * D;
    float4 a0 = {0,0,0,0}, a1 = {0,0,0,0}, a2 = {0,0,0,0}, a3 = {0,0,0,0};
    float4 bacc = {0,0,0,0};
    for (int j = 0; j < N; ++j) {
      const float v = ew[i * N + j];
      if (v > 0.f) {
        const float* Wp = Wl + (size_t)(i * N + j) * (E * D);
        f4acc(a0, f4ld(Wp + (0 * 256 + t) * 4));
        f4acc(a1, f4ld(Wp + (1 * 256 + t) * 4));
        f4acc(a2, f4ld(Wp + (2 * 256 + t) * 4));
        f4acc(a3, f4ld(Wp + (3 * 256 + t) * 4));
        if (t < 16) {
          const float4 w3 = f4ld(Wp + 2 * D * D + t * 4);
          const float4 bv = f4ld(bm + (((size_t)l * N + i) * N + j) * D + t * 4);
          bacc.x += v * w3.x + bv.x;
          bacc.y += v * w3.y + bv.y;
          bacc.z += v * w3.z + bv.z;
          bacc.w += v * w3.w + bv.w;
        }
      }
    }
    float* dst = sw1 + (size_t)unit * D * D;
    *(float4*)(dst + (0 * 256 + t) * 4) = a0;
    *(float4*)(dst + (1 * 256 + t) * 4) = a1;
    *(float4*)(dst + (2 * 256 + t) * 4) = a2;
    *(float4*)(dst + (3 * 256 + t) * 4) = a3;
    if (t < 16) *(float4*)(baseB + (size_t)unit * D + t * 4) = bacc;
  }
  gridbar(bar + 0);

  for (int l = 0; l < L; ++l) {
    const float* sin_p = (l == 0) ? x : s;
    const bool LAST = (l == L - 1);
    const float* Wl = Wm + (size_t)l * N * N * E * D;

    // ================= P1: per-edge K=64 GEMMs + per-node self GEMMs ======
    {
      float (*aT)[64] = (float(*)[64])pool;        // 16KB: aT[k][b] = S[b][jj][k]
      float* wLds = (float*)(pool + 16384);        // 16KB

      const int ne = *nedg;
      for (int u = g; u < ne + N; u += NBLK) {
        int jj;
        const float* wsrc;
        const float* basep;
        float* dst;
        if (u < ne) {
          const int ij = edgeIJ[u];
          jj = ij & 63;
          wsrc = Wl + (size_t)ij * (E * D) + D * D;      // W2 block
          dst = msg + (size_t)u * B * D;
          basep = nullptr;
        } else {
          const int i = u - ne;
          jj = i;
          wsrc = sw1 + ((size_t)l * N + i) * D * D;
          dst = selfmsg + (size_t)i * B * D;
          basep = baseB + ((size_t)l * N + i) * D;
        }
        // stage A^T
        {
          const int bb = t >> 2, q = t & 3;
          const float* ps = sin_p + ((size_t)(bb * N + jj)) * D + q * 16;
          const float4 v0 = f4ld(ps), v1 = f4ld(ps + 4),
                       v2 = f4ld(ps + 8), v3 = f4ld(ps + 12);
          const int k0 = q * 16;
          aT[k0 + 0][bb] = v0.x; aT[k0 + 1][bb] = v0.y;
          aT[k0 + 2][bb] = v0.z; aT[k0 + 3][bb] = v0.w;
          aT[k0 + 4][bb] = v1.x; aT[k0 + 5][bb] = v1.y;
          aT[k0 + 6][bb] = v1.z; aT[k0 + 7][bb] = v1.w;
          aT[k0 + 8][bb] = v2.x; aT[k0 + 9][bb] = v2.y;
          aT[k0 +10][bb] = v2.z; aT[k0 +11][bb] = v2.w;
          aT[k0 +12][bb] = v3.x; aT[k0 +13][bb] = v3.y;
          aT[k0 +14][bb] = v3.z; aT[k0 +15][bb] = v3.w;
        }
        // stage W (16KB, coalesced)
#pragma unroll
        for (int r = 0; r < 4; ++r)
          *(float4*)(wLds + (r * 256 + t) * 4) = f4ld(wsrc + (r * 256 + t) * 4);
        __syncthreads();

        const int td = t & 15, tb = t >> 4;
        float acc[4][4];
        if (basep) {
          const float4 bv = f4ld(basep + td * 4);
#pragma unroll
          for (int r = 0; r < 4; ++r) {
            acc[r][0] = bv.x; acc[r][1] = bv.y;
            acc[r][2] = bv.z; acc[r][3] = bv.w;
          }
        } else {
#pragma unroll
          for (int r = 0; r < 4; ++r)
#pragma unroll
            for (int c2 = 0; c2 < 4; ++c2) acc[r][c2] = 0.f;
        }
#pragma unroll 4
        for (int k = 0; k < D; ++k) {
          const float4 a = *(const float4*)&aT[k][tb * 4];
          const float4 wv = f4ld(wLds + k * D + td * 4);
          const float ar[4] = {a.x, a.y, a.z, a.w};
          const float wc[4] = {wv.x, wv.y, wv.z, wv.w};
#pragma unroll
          for (int r = 0; r < 4; ++r)
#pragma unroll
            for (int c2 = 0; c2 < 4; ++c2) acc[r][c2] += ar[r] * wc[c2];
        }
        float* mp = dst + ((size_t)(tb * 4)) * D + td * 4;
#pragma unroll
        for (int r = 0; r < 4; ++r)
          *(float4*)(mp + (size_t)r * D) =
              make_float4(acc[r][0], acc[r][1], acc[r][2], acc[r][3]);
        __syncthreads();  // LDS reuse by next unit
      }
    }
    gridbar(bar + 1 + 2 * l);

    // ================= P2: update MLP + residual + scan (+ readout) =======
    if (g < B) {
      const int b = g;
      const float* Wul = Wu + (size_t)l * 2 * D * D;
      const float* bul = bu + (size_t)l * D;

      float (*catT)[64] = (float(*)[64])pool;               // 32KB
      float (*sb)[65]   = (float(*)[65])(pool + 32768);     // 16640B
      uint4* nbrL = (uint4*)(pool + 49408);                 // 1KB
      float* degL = (float*)(pool + 50432);
      float* cwL  = (float*)(pool + 50688);
      int*   cntL = (int*)(pool + 50944);

      {
        const int ii = t >> 2, q = t & 3;
        const int cI = cntg[ii];
        const int rb = rowbase[ii];
        float4 a4[4];
#pragma unroll
        for (int kc = 0; kc < 4; ++kc)
          a4[kc] = f4ld(selfmsg + ((size_t)(ii * B + b)) * D + kc * 16 + q * 4);
        for (int e = 0; e < cI; ++e) {
          const float* pm = msg + ((size_t)(rb + e) * B + b) * D;
#pragma unroll
          for (int kc = 0; kc < 4; ++kc)
            f4acc(a4[kc], f4ld(pm + kc * 16 + q * 4));
        }
        const float* ps = sin_p + ((size_t)(b * N + ii)) * D;
#pragma unroll
        for (int kc = 0; kc < 4; ++kc) {
          const int k0 = kc * 16 + q * 4;
          const float4 v = f4ld(ps + k0);
          catT[k0 + 0][ii] = v.x; catT[k0 + 1][ii] = v.y;
          catT[k0 + 2][ii] = v.z; catT[k0 + 3][ii] = v.w;
          catT[D + k0 + 0][ii] = a4[kc].x; catT[D + k0 + 1][ii] = a4[kc].y;
          catT[D + k0 + 2][ii] = a4[kc].z; catT[D + k0 + 3][ii] = a4[kc].w;
        }
      }
      if (t < N) {
        nbrL[t] = nbr4[t];
        degL[t] = degf[t];
        cntL[t] = cntg[t];
        if (LAST) cwL[t] = cwg[t];
      }
      __syncthreads();

      // upd GEMM: lane = i, wave-uniform d-chunk (Wu rows via s_load)
      const int i = t & 63;
      const int d0 = __builtin_amdgcn_readfirstlane(t >> 6) * 16;
      float acc[16];
#pragma unroll
      for (int u = 0; u < 16; ++u) acc[u] = bul[d0 + u];
#pragma unroll 4
      for (int k = 0; k < 2 * D; ++k) {
        const float a = catT[k][i];
        const float* __restrict__ wr = Wul + (size_t)k * D + d0;
#pragma unroll
        for (int u = 0; u < 16; ++u) acc[u] += a * wr[u];
      }
#pragma unroll
      for (int u = 0; u < 16; ++u)
        sb[i][d0 + u] = 0.9f * acc[u] + 0.1f * catT[d0 + u][i];
      __syncthreads();

      // sequential node scan; lane d owns column d (wave 0)
      if (t < N) {
        const int d = t;
        uint4 w = nbrL[0];
        int c = cntL[0];
        float dg = degL[0];
        for (int ii = 0; ii < N; ++ii) {
          uint4 wn = w; int cn = c; float dgn = dg;
          if (ii < N - 1) { wn = nbrL[ii + 1]; cn = cntL[ii + 1]; dgn = degL[ii + 1]; }
          const unsigned wd[4] = {w.x, w.y, w.z, w.w};
          float nb = 0.0f;
#pragma unroll
          for (int q = 0; q < 8; ++q) {
            const int idx = (int)((wd[q >> 2] >> ((q & 3) * 8)) & 63u);
            const float v = sb[idx][d];
            nb += (q < c) ? v : 0.0f;
          }
          if (c > 8) {
#pragma unroll
            for (int q = 8; q < 16; ++q) {
              const int idx = (int)((wd[q >> 2] >> ((q & 3) * 8)) & 63u);
              const float v = sb[idx][d];
              nb += (q < c) ? v : 0.0f;
            }
            for (int q = 16; q < c; ++q) nb += sb[nfull[ii * N + q]][d];
          }
          const float avg = nb / fmaxf(dg, 1.0f);
          const float cur = sb[ii][d];
          sb[ii][d] = (dg > 0.0f) ? (0.95f * cur + 0.05f * avg) : cur;
          w = wn; c = cn; dg = dgn;
        }
        if (LAST) {
          float gg = 0.0f;
          for (int i2 = 0; i2 < N; ++i2) gg += cwL[i2] * sb[i2][d];
          float o = bo[d];
          for (int k2 = 0; k2 < D; ++k2) o += __shfl(gg, k2, 64) * Wo[k2 * D + d];
          out[(size_t)b * D + d] = o;
        }
      }

      if (!LAST) {
        __syncthreads();
        const int ii = t >> 2, q = t & 3;
        float* ps = s + ((size_t)(b * N + ii)) * D;
#pragma unroll
        for (int kc = 0; kc < 4; ++kc) {
          const int k0 = kc * 16 + q * 4;
          float4 v;
          v.x = sb[ii][k0 + 0]; v.y = sb[ii][k0 + 1];
          v.z = sb[ii][k0 + 2]; v.w = sb[ii][k0 + 3];
          *(float4*)(ps + k0) = v;
        }
      }
    }
    if (l < L - 1) gridbar(bar + 2 + 2 * l);
  }
}

}  // namespace

extern "C" void kernel_launch(void* const* d_in, const int* in_sizes, int n_in,
                              void* d_out, int out_size, void* d_ws, size_t ws_size,
                              hipStream_t stream)
{
  const float* x  = (const float*)d_in[0];
  const float* ew = (const float*)d_in[1];
  const float* Wm = (const float*)d_in[2];
  const float* bm = (const float*)d_in[3];
  const float* Wu = (const float*)d_in[4];
  const float* bu = (const float*)d_in[5];
  const float* Wo = (const float*)d_in[6];
  const float* bo = (const float*)d_in[7];
  float* out = (float*)d_out;

  int L = in_sizes[2] / (N * N * E * D);  // = 3
  if (L > LMAX) L = LMAX;

  hipMemsetAsync(d_ws, 0, 256, stream);  // zero grid-barrier counters
  k_fused<<<NBLK, 256, 0, stream>>>(x, ew, Wm, bm, Wu, bu, Wo, bo, out,
                                    (char*)d_ws, L);
}